// Round 17
// baseline (267.348 us; speedup 1.0000x reference)
//
#include <hip/hip_runtime.h>

#define HID 128
#define C2 256   // HEADS*HID
#define NEG 0.2f
#define L2E 1.44269504088896340736f
#define LROW 264  // LDS row stride in shorts: 16B-aligned, breaks 256-stride bank pattern

typedef __bf16 v8bf __attribute__((ext_vector_type(8)));
typedef float  v4f  __attribute__((ext_vector_type(4)));
typedef float  v2f  __attribute__((ext_vector_type(2)));
typedef unsigned short us8 __attribute__((ext_vector_type(8)));

__device__ __forceinline__ float bf2f(unsigned short u) {
    union { float f; unsigned int i; } v; v.i = ((unsigned int)u) << 16; return v.f;
}
__device__ __forceinline__ unsigned short f2bf(float f) {
    union { float f; unsigned int i; } v; v.f = f;
    unsigned int r = v.i + 0x7FFFu + ((v.i >> 16) & 1u);
    return (unsigned short)(r >> 16);
}
__device__ __forceinline__ float lrelu(float x) { return x > 0.f ? x : NEG * x; }

// ---------------- prep: 3x packB + hist_rank fused ----------------
__device__ __forceinline__ void packB_body(const float* __restrict__ W,
                                           unsigned short* __restrict__ out,
                                           int K, int N, int idx) {
    int ksteps = K >> 5;
    int total = (N >> 4) * ksteps * 64;
    if (idx >= total) return;
    int lane = idx & 63;
    int rest = idx >> 6;
    int tt = rest / ksteps, k0 = rest - tt * ksteps;
    int n = (tt >> 3) * 128 + (lane & 15) * 8 + (tt & 7);
    int kb = k0 * 32 + (lane >> 4) * 8;
    us8 v;
#pragma unroll
    for (int j = 0; j < 8; ++j) v[j] = f2bf(W[(size_t)(kb + j) * N + n]);
    *(us8*)(out + (size_t)idx * 8) = v;
}

__global__ __launch_bounds__(256) void prep_kernel(const float* __restrict__ W1, unsigned short* W1p,
                                                   const float* __restrict__ W2, unsigned short* W2p,
                                                   const float* __restrict__ Wp1, unsigned short* Wp1p,
                                                   const int* __restrict__ ei, int* __restrict__ cnt,
                                                   int* __restrict__ rank, int E,
                                                   int b1, int b2, int b3) {
    int b = blockIdx.x;
    if (b < b1) { packB_body(W1, W1p, HID, C2, b * 256 + threadIdx.x); return; }
    b -= b1;
    if (b < b2) { packB_body(W2, W2p, C2, C2, b * 256 + threadIdx.x); return; }
    b -= b2;
    if (b < b3) { packB_body(Wp1, Wp1p, C2, HID, b * 256 + threadIdx.x); return; }
    b -= b3;
    int i = b * 256 + threadIdx.x;
    if (i >= E) return;
    int d = ei[E + i];
    rank[i] = atomicAdd(&cnt[d], 1);
}

// ---------------- scans: scanA + merged scanBC ----------------
__global__ __launch_bounds__(256) void scanA(const int* __restrict__ cnt, int* __restrict__ rs,
                                             int* __restrict__ part, int N) {
    __shared__ int s[256];
    int t = threadIdx.x, i = blockIdx.x * 256 + t;
    int v = (i < N) ? cnt[i] : 0;
    s[t] = v; __syncthreads();
    for (int off = 1; off < 256; off <<= 1) {
        int x = (t >= off) ? s[t - off] : 0;
        __syncthreads();
        s[t] += x;
        __syncthreads();
    }
    if (i < N) rs[i] = s[t] - v;
    if (t == 255) part[blockIdx.x] = s[255];
}

__global__ __launch_bounds__(256) void scanBC(int* __restrict__ rs, const int* __restrict__ part,
                                              int N, int E, int nchunk) {
    __shared__ int ls[256];
    int t = threadIdx.x;
    int v = (t < nchunk) ? part[t] : 0;
    ls[t] = v; __syncthreads();
    for (int off = 1; off < 256; off <<= 1) {
        int x = (t >= off) ? ls[t - off] : 0;
        __syncthreads();
        ls[t] += x;
        __syncthreads();
    }
    int base = (blockIdx.x > 0) ? ls[blockIdx.x - 1] : 0;
    int i = blockIdx.x * 256 + t;
    if (i < N) rs[i] += base;
    if (i == 0) rs[N] = E;
}

// ---------------- GEMM layer 1: fused alpha dots + coalesced fp8 store ----------------
template<bool AFP32, int G, int KSTEPS>
__global__ __launch_bounds__(256) void gemm_alpha(const void* __restrict__ Av,
                                                  const unsigned short* __restrict__ Bp,
                                                  const float* __restrict__ asrc,
                                                  const float* __restrict__ adst,
                                                  float* __restrict__ asd,
                                                  unsigned char* __restrict__ C,
                                                  int M, int N, int gemmBlocks,
                                                  const int* __restrict__ ei,
                                                  const int* __restrict__ rs,
                                                  const int* __restrict__ rank,
                                                  int* __restrict__ csr, int E) {
    if (blockIdx.x >= gemmBlocks) {
        int i = (blockIdx.x - gemmBlocks) * 256 + threadIdx.x;
        if (i < E) {
            int s = ei[i], d = ei[E + i];
            csr[rs[d] + rank[i]] = s;
        }
        return;
    }
    constexpr int K = KSTEPS * 32;
    int ngrp = N >> 7;
    int mtiles = M >> 4;
    int w = (blockIdx.x << 2) + (threadIdx.x >> 6);
    int groups = (mtiles + G - 1) / G;
    int mp = w / ngrp, g = w - mp * ngrp;
    if (mp >= groups) return;
    int lane = threadIdx.x & 63;
    int l16 = lane & 15, quad = lane >> 4;
    int mt0 = mp * G;

    int mrow[G];
#pragma unroll
    for (int gi = 0; gi < G; ++gi) {
        int mt = mt0 + gi;
        mrow[gi] = (mt < mtiles ? mt : mtiles - 1) * 16 + l16;
    }

    const unsigned short* Bf = Bp + ((size_t)(g * 8) * KSTEPS << 9) + lane * 8;
    v4f acc[G][8];
#pragma unroll
    for (int gi = 0; gi < G; ++gi)
#pragma unroll
        for (int t = 0; t < 8; ++t) acc[gi][t] = (v4f){0, 0, 0, 0};

#pragma unroll
    for (int k0 = 0; k0 < KSTEPS; ++k0) {
        v8bf bfr[8];
#pragma unroll
        for (int t = 0; t < 8; ++t)
            bfr[t] = *(const v8bf*)(Bf + ((size_t)(t * KSTEPS + k0) << 9));
        v8bf a[G];
        if (AFP32) {
            const float* A = (const float*)Av;
#pragma unroll
            for (int gi = 0; gi < G; ++gi) {
                const float* p = A + (size_t)mrow[gi] * K + k0 * 32 + quad * 8;
                float4 u0 = *(const float4*)p, u1 = *(const float4*)(p + 4);
                a[gi][0]=(__bf16)u0.x; a[gi][1]=(__bf16)u0.y; a[gi][2]=(__bf16)u0.z; a[gi][3]=(__bf16)u0.w;
                a[gi][4]=(__bf16)u1.x; a[gi][5]=(__bf16)u1.y; a[gi][6]=(__bf16)u1.z; a[gi][7]=(__bf16)u1.w;
            }
        } else {
            const unsigned short* A = (const unsigned short*)Av;
#pragma unroll
            for (int gi = 0; gi < G; ++gi)
                a[gi] = *(const v8bf*)(A + (size_t)mrow[gi] * K + k0 * 32 + quad * 8);
        }
#pragma unroll
        for (int t = 0; t < 8; ++t)
#pragma unroll
            for (int gi = 0; gi < G; ++gi)
                acc[gi][t] = __builtin_amdgcn_mfma_f32_16x16x32_bf16(a[gi], bfr[t], acc[gi][t], 0, 0, 0);
    }

    int n0 = g << 7;
    int cb = n0 + l16 * 8;
    float sv[8], dv[8];
#pragma unroll
    for (int t = 0; t < 8; ++t) {
        sv[t] = asrc[cb + t];
        dv[t] = adst[cb + t];
    }
#pragma unroll
    for (int gi = 0; gi < G; ++gi) {
        int mt = mt0 + gi;
        if (mt >= mtiles) break;
        int row0 = mt * 16 + quad * 4;
#pragma unroll
        for (int r = 0; r < 4; ++r) {
            float sa = 0.f, sd = 0.f;
#pragma unroll
            for (int t = 0; t < 8; ++t) {
                sa += acc[gi][t][r] * sv[t];
                sd += acc[gi][t][r] * dv[t];
            }
            unsigned int w0 = __builtin_amdgcn_cvt_pk_fp8_f32(acc[gi][0][r], acc[gi][1][r], 0, false);
            w0 = __builtin_amdgcn_cvt_pk_fp8_f32(acc[gi][2][r], acc[gi][3][r], w0, true);
            unsigned int w1 = __builtin_amdgcn_cvt_pk_fp8_f32(acc[gi][4][r], acc[gi][5][r], 0, false);
            w1 = __builtin_amdgcn_cvt_pk_fp8_f32(acc[gi][6][r], acc[gi][7][r], w1, true);
            *(uint2*)(C + (size_t)(row0 + r) * N + cb) = (uint2){w0, w1};
#pragma unroll
            for (int off = 8; off; off >>= 1) {
                sa += __shfl_xor(sa, off);
                sd += __shfl_xor(sd, off);
            }
            if (l16 == 0) {
                int row = row0 + r;
                asd[(size_t)row * 4 + g]     = sa * L2E;
                asd[(size_t)row * 4 + 2 + g] = sd * L2E;
            }
        }
    }
}

// ---------------- agg phase v2: 16 dests/block, 2 half-groups of 8 lanes per dest ----
// Straggler fix: each dest's edge walk is split across two 8-lane half-groups
// (interleaved edges i = beg+half, i += 2) -> serial latency chain per dest
// halves; block-barrier straggler (max over 16 dests) halves. Grid unchanged
// (3125 — round-9 lesson). Halves combine in-register via __shfl_xor(.,8)
// (same wave by construction; epilogue-only cross-lane, not per-edge).
// Self-loop handled by half 1 (floor(deg/2) edges — balances half 0's ceil).
__device__ __forceinline__ void agg16_to_lds(const int* __restrict__ rs,
                                             const int* __restrict__ csr,
                                             const unsigned char* __restrict__ h,
                                             const float* __restrict__ asd,
                                             const float* __restrict__ bias,
                                             unsigned short* __restrict__ sA,
                                             int rowbase, int M, int tid) {
    int dgrp = tid >> 4;                // dest 0..15 within block
    int half = (tid >> 3) & 1;          // half-group 0/1
    int sub = tid & 7;                  // 32B slice of the 256B row
    int d = rowbase + dgrp;
    if (d >= M) return;   // never taken at N=50000; barriers are in caller
    int head = sub >> 2;                // cols [0,128) -> head 0, [128,256) -> head 1
    int beg = rs[d], end = rs[d + 1];
    float adh = asd[(size_t)d * 4 + 2 + head];
    int cbase = sub * 32;
    const unsigned char* hc = h + cbase;
    v2f acc[16];
#pragma unroll
    for (int j = 0; j < 16; ++j) acc[j] = (v2f){0, 0};
    float den = 0.f;
#pragma unroll 2
    for (int i = beg + half; i < end; i += 2) {
        int s = csr[i];
        float wgt = __builtin_amdgcn_exp2f(lrelu(asd[(size_t)s * 4 + head] + adh));
        den += wgt;
        const unsigned char* row = hc + ((size_t)s << 8);
        uint4 u0 = *(const uint4*)row;
        uint4 u1 = *(const uint4*)(row + 16);
        v2f w2 = {wgt, wgt};
        acc[0]  += w2 * __builtin_amdgcn_cvt_pk_f32_fp8(u0.x, false);
        acc[1]  += w2 * __builtin_amdgcn_cvt_pk_f32_fp8(u0.x, true);
        acc[2]  += w2 * __builtin_amdgcn_cvt_pk_f32_fp8(u0.y, false);
        acc[3]  += w2 * __builtin_amdgcn_cvt_pk_f32_fp8(u0.y, true);
        acc[4]  += w2 * __builtin_amdgcn_cvt_pk_f32_fp8(u0.z, false);
        acc[5]  += w2 * __builtin_amdgcn_cvt_pk_f32_fp8(u0.z, true);
        acc[6]  += w2 * __builtin_amdgcn_cvt_pk_f32_fp8(u0.w, false);
        acc[7]  += w2 * __builtin_amdgcn_cvt_pk_f32_fp8(u0.w, true);
        acc[8]  += w2 * __builtin_amdgcn_cvt_pk_f32_fp8(u1.x, false);
        acc[9]  += w2 * __builtin_amdgcn_cvt_pk_f32_fp8(u1.x, true);
        acc[10] += w2 * __builtin_amdgcn_cvt_pk_f32_fp8(u1.y, false);
        acc[11] += w2 * __builtin_amdgcn_cvt_pk_f32_fp8(u1.y, true);
        acc[12] += w2 * __builtin_amdgcn_cvt_pk_f32_fp8(u1.z, false);
        acc[13] += w2 * __builtin_amdgcn_cvt_pk_f32_fp8(u1.z, true);
        acc[14] += w2 * __builtin_amdgcn_cvt_pk_f32_fp8(u1.w, false);
        acc[15] += w2 * __builtin_amdgcn_cvt_pk_f32_fp8(u1.w, true);
    }
    if (half) {
        // self-loop term (src = d), not present in csr
        float wS = __builtin_amdgcn_exp2f(lrelu(asd[(size_t)d * 4 + head] + adh));
        den += wS;
        const unsigned char* row = hc + ((size_t)d << 8);
        uint4 u0 = *(const uint4*)row;
        uint4 u1 = *(const uint4*)(row + 16);
        v2f wsv = {wS, wS};
        acc[0]  += wsv * __builtin_amdgcn_cvt_pk_f32_fp8(u0.x, false);
        acc[1]  += wsv * __builtin_amdgcn_cvt_pk_f32_fp8(u0.x, true);
        acc[2]  += wsv * __builtin_amdgcn_cvt_pk_f32_fp8(u0.y, false);
        acc[3]  += wsv * __builtin_amdgcn_cvt_pk_f32_fp8(u0.y, true);
        acc[4]  += wsv * __builtin_amdgcn_cvt_pk_f32_fp8(u0.z, false);
        acc[5]  += wsv * __builtin_amdgcn_cvt_pk_f32_fp8(u0.z, true);
        acc[6]  += wsv * __builtin_amdgcn_cvt_pk_f32_fp8(u0.w, false);
        acc[7]  += wsv * __builtin_amdgcn_cvt_pk_f32_fp8(u0.w, true);
        acc[8]  += wsv * __builtin_amdgcn_cvt_pk_f32_fp8(u1.x, false);
        acc[9]  += wsv * __builtin_amdgcn_cvt_pk_f32_fp8(u1.x, true);
        acc[10] += wsv * __builtin_amdgcn_cvt_pk_f32_fp8(u1.y, false);
        acc[11] += wsv * __builtin_amdgcn_cvt_pk_f32_fp8(u1.y, true);
        acc[12] += wsv * __builtin_amdgcn_cvt_pk_f32_fp8(u1.z, false);
        acc[13] += wsv * __builtin_amdgcn_cvt_pk_f32_fp8(u1.z, true);
        acc[14] += wsv * __builtin_amdgcn_cvt_pk_f32_fp8(u1.w, false);
        acc[15] += wsv * __builtin_amdgcn_cvt_pk_f32_fp8(u1.w, true);
    }
    // combine the two half-groups: lane^8 holds the same cols, other edge half
#pragma unroll
    for (int j = 0; j < 16; ++j) {
        acc[j].x += __shfl_xor(acc[j].x, 8);
        acc[j].y += __shfl_xor(acc[j].y, 8);
    }
    den += __shfl_xor(den, 8);
    if (!half) {
        float rden = 1.f / (den + 1e-16f);
        unsigned short* dst = sA + dgrp * LROW + cbase;
#pragma unroll
        for (int c = 0; c < 4; ++c) {
            us8 o;
#pragma unroll
            for (int j = 0; j < 4; ++j) {
                o[2 * j]     = f2bf(fmaxf(acc[c * 4 + j].x * rden + bias[cbase + c * 8 + 2 * j], 0.f));
                o[2 * j + 1] = f2bf(fmaxf(acc[c * 4 + j].y * rden + bias[cbase + c * 8 + 2 * j + 1], 0.f));
            }
            *(us8*)(dst + c * 8) = o;
        }
    }
}

// ---------------- fused: agg(L1) -> LDS -> gemm(L2) tile b ----------------
// ALL 4 waves active in the gemm phase (wave wv -> group g=wv&1, frag-half
// hh=wv>>1, 4 frags each). Alpha-dot halves combine via small LDS + 2nd barrier.
template<int KSTEPS>
__global__ __launch_bounds__(256) void fused_agg_gemm(const int* __restrict__ rs,
                                                      const int* __restrict__ csr,
                                                      const unsigned char* __restrict__ hIn,
                                                      const float* __restrict__ asdIn,
                                                      const float* __restrict__ biasIn,
                                                      const unsigned short* __restrict__ Bp,
                                                      const float* __restrict__ asrc,
                                                      const float* __restrict__ adst,
                                                      float* __restrict__ asdOut,
                                                      unsigned char* __restrict__ C,
                                                      int M) {
    __shared__ __align__(16) unsigned short sA[16 * LROW];
    __shared__ float sS[2][2][16], sD[2][2][16];   // [hh][g][row16]
    int tid = threadIdx.x;
    int rowbase = blockIdx.x * 16;
    agg16_to_lds(rs, csr, hIn, asdIn, biasIn, sA, rowbase, M, tid);
    __syncthreads();

    int wv = tid >> 6;
    int g  = wv & 1;                      // n-group 0/1
    int hh = wv >> 1;                     // frag half 0/1
    int lane = tid & 63;
    int l16 = lane & 15, quad = lane >> 4;

    const unsigned short* Bf = Bp + ((size_t)(g * 8) * KSTEPS << 9) + lane * 8;
    v4f acc[4];
#pragma unroll
    for (int t = 0; t < 4; ++t) acc[t] = (v4f){0, 0, 0, 0};
#pragma unroll
    for (int k0 = 0; k0 < KSTEPS; ++k0) {
        v8bf bfr[4];
#pragma unroll
        for (int t = 0; t < 4; ++t)
            bfr[t] = *(const v8bf*)(Bf + ((size_t)((hh * 4 + t) * KSTEPS + k0) << 9));
        v8bf a = *(const v8bf*)(sA + l16 * LROW + k0 * 32 + quad * 8);
#pragma unroll
        for (int t = 0; t < 4; ++t)
            acc[t] = __builtin_amdgcn_mfma_f32_16x16x32_bf16(a, bfr[t], acc[t], 0, 0, 0);
    }

    int n0 = g << 7;
    int cb = n0 + l16 * 8 + hh * 4;       // this wave's 4 consecutive cols
    float sv[4], dv[4];
#pragma unroll
    for (int t = 0; t < 4; ++t) {
        sv[t] = asrc[cb + t];
        dv[t] = adst[cb + t];
    }
    int row0q = quad * 4;
#pragma unroll
    for (int r = 0; r < 4; ++r) {
        float sa = 0.f, sd = 0.f;
#pragma unroll
        for (int t = 0; t < 4; ++t) {
            sa += acc[t][r] * sv[t];
            sd += acc[t][r] * dv[t];
        }
        unsigned int w0 = __builtin_amdgcn_cvt_pk_fp8_f32(acc[0][r], acc[1][r], 0, false);
        w0 = __builtin_amdgcn_cvt_pk_fp8_f32(acc[2][r], acc[3][r], w0, true);
        *(unsigned int*)(C + (size_t)(rowbase + row0q + r) * C2 + cb) = w0;
#pragma unroll
        for (int off = 8; off; off >>= 1) {
            sa += __shfl_xor(sa, off);
            sd += __shfl_xor(sd, off);
        }
        if (l16 == 0) {
            sS[hh][g][row0q + r] = sa;
            sD[hh][g][row0q + r] = sd;
        }
    }
    __syncthreads();
    if (tid < 32) {
        int row16 = tid & 15, gg = tid >> 4;
        float sa = (sS[0][gg][row16] + sS[1][gg][row16]) * L2E;
        float sd = (sD[0][gg][row16] + sD[1][gg][row16]) * L2E;
        int row = rowbase + row16;
        asdOut[(size_t)row * 4 + gg]     = sa;
        asdOut[(size_t)row * 4 + 2 + gg] = sd;
    }
}

// ---------------- fused: agg(L2) -> LDS -> post-MLP tile b ----------------
// ALL 4 waves active in the MLP phase (wave wv -> frags {2wv, 2wv+1}).
template<int KSTEPS>
__global__ __launch_bounds__(256) void fused_agg_final(const int* __restrict__ rs,
                                                       const int* __restrict__ csr,
                                                       const unsigned char* __restrict__ hIn,
                                                       const float* __restrict__ asdIn,
                                                       const float* __restrict__ biasIn,
                                                       const unsigned short* __restrict__ Bp,
                                                       const float* __restrict__ bp1,
                                                       const float* __restrict__ wp2,
                                                       const float* __restrict__ bp2,
                                                       float* __restrict__ out,
                                                       int M) {
    __shared__ __align__(16) unsigned short sA[16 * LROW];
    __shared__ float sF[4][16];
    int tid = threadIdx.x;
    int rowbase = blockIdx.x * 16;
    agg16_to_lds(rs, csr, hIn, asdIn, biasIn, sA, rowbase, M, tid);
    __syncthreads();

    int wv = tid >> 6;
    int lane = tid & 63;
    int l16 = lane & 15, quad = lane >> 4;

    const unsigned short* Bf = Bp + lane * 8;
    v4f acc[2];
#pragma unroll
    for (int t = 0; t < 2; ++t) acc[t] = (v4f){0, 0, 0, 0};
#pragma unroll
    for (int k0 = 0; k0 < KSTEPS; ++k0) {
        v8bf a = *(const v8bf*)(sA + l16 * LROW + k0 * 32 + quad * 8);
#pragma unroll
        for (int t = 0; t < 2; ++t) {
            v8bf bfr = *(const v8bf*)(Bf + ((size_t)((wv * 2 + t) * KSTEPS + k0) << 9));
            acc[t] = __builtin_amdgcn_mfma_f32_16x16x32_bf16(a, bfr, acc[t], 0, 0, 0);
        }
    }
    int cb = l16 * 8;
    float wv2[2], bv2[2];
#pragma unroll
    for (int t = 0; t < 2; ++t) {
        wv2[t] = wp2[cb + wv * 2 + t];
        bv2[t] = bp1[cb + wv * 2 + t];
    }
    int row0q = quad * 4;
#pragma unroll
    for (int r = 0; r < 4; ++r) {
        float s = (acc[0][r] + bv2[0]) * wv2[0] + (acc[1][r] + bv2[1]) * wv2[1];
#pragma unroll
        for (int off = 8; off; off >>= 1) s += __shfl_xor(s, off);
        if (l16 == 0) sF[wv][row0q + r] = s;
    }
    __syncthreads();
    if (tid < 16) {
        float s = sF[0][tid] + sF[1][tid] + sF[2][tid] + sF[3][tid] + bp2[0];
        out[rowbase + tid] = 1.f / (1.f + __expf(-s));
    }
}

extern "C" void kernel_launch(void* const* d_in, const int* in_sizes, int n_in,
                              void* d_out, int out_size, void* d_ws, size_t ws_size,
                              hipStream_t stream) {
    const float* x   = (const float*)d_in[0];
    const int*   ei  = (const int*)d_in[1];
    const float* W1  = (const float*)d_in[2];
    const float* as1 = (const float*)d_in[3];
    const float* ad1 = (const float*)d_in[4];
    const float* b1  = (const float*)d_in[5];
    const float* W2  = (const float*)d_in[6];
    const float* as2 = (const float*)d_in[7];
    const float* ad2 = (const float*)d_in[8];
    const float* b2  = (const float*)d_in[9];
    const float* Wp1 = (const float*)d_in[10];
    const float* bp1 = (const float*)d_in[11];
    const float* Wp2 = (const float*)d_in[12];
    const float* bp2 = (const float*)d_in[13];
    float* out = (float*)d_out;

    int NN = in_sizes[0] / HID;   // 50000
    int E  = in_sizes[1] / 2;     // 800000

    char* ws = (char*)d_ws;
    size_t off = 0;
    auto alloc = [&](size_t bytes) -> char* {
        char* p = ws + off;
        off += (bytes + 255) & ~(size_t)255;
        return p;
    };
    unsigned char*  bufH1 = (unsigned char*)alloc((size_t)NN * C2);      // h1, fp8 e4m3
    unsigned char*  bufH2 = (unsigned char*)alloc((size_t)NN * C2);      // h2, fp8 e4m3
    float* asd1 = (float*)alloc((size_t)NN * 4 * sizeof(float));
    float* asd2 = (float*)alloc((size_t)NN * 4 * sizeof(float));
    int* rs    = (int*)alloc((size_t)(NN + 1) * 4);
    int* cnt   = (int*)alloc((size_t)NN * 4);
    int* rank  = (int*)alloc((size_t)E * 4);
    int* csr   = (int*)alloc((size_t)E * 4);
    int* part  = (int*)alloc(1024);
    unsigned short* W1p  = (unsigned short*)alloc((size_t)HID * C2 * 2);  // packed
    unsigned short* W2p  = (unsigned short*)alloc((size_t)C2 * C2 * 2);
    unsigned short* Wp1p = (unsigned short*)alloc((size_t)C2 * HID * 2);

    int nchunk = (NN + 255) / 256;
    int eblk   = (E + 255) / 256;

    // prep: weight packing + hist/rank (fused)
    int pb1 = (HID * C2 / 8 + 255) / 256;
    int pb2 = (C2 * C2 / 8 + 255) / 256;
    int pb3 = (C2 * HID / 8 + 255) / 256;
    hipMemsetAsync(cnt, 0, (size_t)NN * 4, stream);
    prep_kernel<<<pb1 + pb2 + pb3 + eblk, 256, 0, stream>>>(W1, W1p, W2, W2p, Wp1, Wp1p,
                                                            ei, cnt, rank, E, pb1, pb2, pb3);
    scanA<<<nchunk, 256, 0, stream>>>(cnt, rs, part, NN);
    scanBC<<<nchunk, 256, 0, stream>>>(rs, part, NN, E, nchunk);

    const int G = 1;
    int mtiles = NN / 16;                     // 3125
    int gemmBlocks = (mtiles * 2 + 3) / 4;    // 1563 (ngrp=2)
    int fuseGrid = mtiles;                    // 3125: agg grid preserved

    // layer 1 (A = fp32 x, K=128) + fused alpha dots, scatter piggy-backed
    gemm_alpha<true, G, 4><<<gemmBlocks + eblk, 256, 0, stream>>>(x, W1p, as1, ad1, asd1, bufH1,
                                                                  NN, C2, gemmBlocks,
                                                                  ei, rs, rank, csr, E);
    // fused: agg(L1) -> LDS -> gemm(L2)+alpha  (reads h1/asd1, writes h2/asd2)
    fused_agg_gemm<8><<<fuseGrid, 256, 0, stream>>>(rs, csr, bufH1, asd1, b1,
                                                    W2p, as2, ad2, asd2, bufH2, NN);
    // fused: agg(L2) -> LDS -> post-MLP
    fused_agg_final<8><<<fuseGrid, 256, 0, stream>>>(rs, csr, bufH2, asd2, b2,
                                                     Wp1p, bp1, Wp2, bp2, out, NN);
}

// Round 18
// 256.355 us; speedup vs baseline: 1.0429x; 1.0429x over previous
//
#include <hip/hip_runtime.h>

#define HID 128
#define C2 256   // HEADS*HID
#define NEG 0.2f
#define L2E 1.44269504088896340736f
#define LROW 264  // LDS row stride in shorts: 16B-aligned, breaks 256-stride bank pattern

typedef __bf16 v8bf __attribute__((ext_vector_type(8)));
typedef float  v4f  __attribute__((ext_vector_type(4)));
typedef float  v2f  __attribute__((ext_vector_type(2)));
typedef unsigned short us8 __attribute__((ext_vector_type(8)));

__device__ __forceinline__ float bf2f(unsigned short u) {
    union { float f; unsigned int i; } v; v.i = ((unsigned int)u) << 16; return v.f;
}
__device__ __forceinline__ unsigned short f2bf(float f) {
    union { float f; unsigned int i; } v; v.f = f;
    unsigned int r = v.i + 0x7FFFu + ((v.i >> 16) & 1u);
    return (unsigned short)(r >> 16);
}
__device__ __forceinline__ float lrelu(float x) { return x > 0.f ? x : NEG * x; }

// ---------------- prep: 3x packB + hist_rank fused ----------------
__device__ __forceinline__ void packB_body(const float* __restrict__ W,
                                           unsigned short* __restrict__ out,
                                           int K, int N, int idx) {
    int ksteps = K >> 5;
    int total = (N >> 4) * ksteps * 64;
    if (idx >= total) return;
    int lane = idx & 63;
    int rest = idx >> 6;
    int tt = rest / ksteps, k0 = rest - tt * ksteps;
    int n = (tt >> 3) * 128 + (lane & 15) * 8 + (tt & 7);
    int kb = k0 * 32 + (lane >> 4) * 8;
    us8 v;
#pragma unroll
    for (int j = 0; j < 8; ++j) v[j] = f2bf(W[(size_t)(kb + j) * N + n]);
    *(us8*)(out + (size_t)idx * 8) = v;
}

__global__ __launch_bounds__(256) void prep_kernel(const float* __restrict__ W1, unsigned short* W1p,
                                                   const float* __restrict__ W2, unsigned short* W2p,
                                                   const float* __restrict__ Wp1, unsigned short* Wp1p,
                                                   const int* __restrict__ ei, int* __restrict__ cnt,
                                                   int* __restrict__ rank, int E,
                                                   int b1, int b2, int b3) {
    int b = blockIdx.x;
    if (b < b1) { packB_body(W1, W1p, HID, C2, b * 256 + threadIdx.x); return; }
    b -= b1;
    if (b < b2) { packB_body(W2, W2p, C2, C2, b * 256 + threadIdx.x); return; }
    b -= b2;
    if (b < b3) { packB_body(Wp1, Wp1p, C2, HID, b * 256 + threadIdx.x); return; }
    b -= b3;
    int i = b * 256 + threadIdx.x;
    if (i >= E) return;
    int d = ei[E + i];
    rank[i] = atomicAdd(&cnt[d], 1);
}

// ---------------- scans: scanA + merged scanBC ----------------
__global__ __launch_bounds__(256) void scanA(const int* __restrict__ cnt, int* __restrict__ rs,
                                             int* __restrict__ part, int N) {
    __shared__ int s[256];
    int t = threadIdx.x, i = blockIdx.x * 256 + t;
    int v = (i < N) ? cnt[i] : 0;
    s[t] = v; __syncthreads();
    for (int off = 1; off < 256; off <<= 1) {
        int x = (t >= off) ? s[t - off] : 0;
        __syncthreads();
        s[t] += x;
        __syncthreads();
    }
    if (i < N) rs[i] = s[t] - v;
    if (t == 255) part[blockIdx.x] = s[255];
}

__global__ __launch_bounds__(256) void scanBC(int* __restrict__ rs, const int* __restrict__ part,
                                              int N, int E, int nchunk) {
    __shared__ int ls[256];
    int t = threadIdx.x;
    int v = (t < nchunk) ? part[t] : 0;
    ls[t] = v; __syncthreads();
    for (int off = 1; off < 256; off <<= 1) {
        int x = (t >= off) ? ls[t - off] : 0;
        __syncthreads();
        ls[t] += x;
        __syncthreads();
    }
    int base = (blockIdx.x > 0) ? ls[blockIdx.x - 1] : 0;
    int i = blockIdx.x * 256 + t;
    if (i < N) rs[i] += base;
    if (i == 0) rs[N] = E;
}

// ---------------- GEMM layer 1: fused alpha dots + coalesced fp8 store ----------------
template<bool AFP32, int G, int KSTEPS>
__global__ __launch_bounds__(256) void gemm_alpha(const void* __restrict__ Av,
                                                  const unsigned short* __restrict__ Bp,
                                                  const float* __restrict__ asrc,
                                                  const float* __restrict__ adst,
                                                  float* __restrict__ asd,
                                                  unsigned char* __restrict__ C,
                                                  int M, int N, int gemmBlocks,
                                                  const int* __restrict__ ei,
                                                  const int* __restrict__ rs,
                                                  const int* __restrict__ rank,
                                                  int* __restrict__ csr, int E) {
    if (blockIdx.x >= gemmBlocks) {
        int i = (blockIdx.x - gemmBlocks) * 256 + threadIdx.x;
        if (i < E) {
            int s = ei[i], d = ei[E + i];
            csr[rs[d] + rank[i]] = s;
        }
        return;
    }
    constexpr int K = KSTEPS * 32;
    int ngrp = N >> 7;
    int mtiles = M >> 4;
    int w = (blockIdx.x << 2) + (threadIdx.x >> 6);
    int groups = (mtiles + G - 1) / G;
    int mp = w / ngrp, g = w - mp * ngrp;
    if (mp >= groups) return;
    int lane = threadIdx.x & 63;
    int l16 = lane & 15, quad = lane >> 4;
    int mt0 = mp * G;

    int mrow[G];
#pragma unroll
    for (int gi = 0; gi < G; ++gi) {
        int mt = mt0 + gi;
        mrow[gi] = (mt < mtiles ? mt : mtiles - 1) * 16 + l16;
    }

    const unsigned short* Bf = Bp + ((size_t)(g * 8) * KSTEPS << 9) + lane * 8;
    v4f acc[G][8];
#pragma unroll
    for (int gi = 0; gi < G; ++gi)
#pragma unroll
        for (int t = 0; t < 8; ++t) acc[gi][t] = (v4f){0, 0, 0, 0};

#pragma unroll
    for (int k0 = 0; k0 < KSTEPS; ++k0) {
        v8bf bfr[8];
#pragma unroll
        for (int t = 0; t < 8; ++t)
            bfr[t] = *(const v8bf*)(Bf + ((size_t)(t * KSTEPS + k0) << 9));
        v8bf a[G];
        if (AFP32) {
            const float* A = (const float*)Av;
#pragma unroll
            for (int gi = 0; gi < G; ++gi) {
                const float* p = A + (size_t)mrow[gi] * K + k0 * 32 + quad * 8;
                float4 u0 = *(const float4*)p, u1 = *(const float4*)(p + 4);
                a[gi][0]=(__bf16)u0.x; a[gi][1]=(__bf16)u0.y; a[gi][2]=(__bf16)u0.z; a[gi][3]=(__bf16)u0.w;
                a[gi][4]=(__bf16)u1.x; a[gi][5]=(__bf16)u1.y; a[gi][6]=(__bf16)u1.z; a[gi][7]=(__bf16)u1.w;
            }
        } else {
            const unsigned short* A = (const unsigned short*)Av;
#pragma unroll
            for (int gi = 0; gi < G; ++gi)
                a[gi] = *(const v8bf*)(A + (size_t)mrow[gi] * K + k0 * 32 + quad * 8);
        }
#pragma unroll
        for (int t = 0; t < 8; ++t)
#pragma unroll
            for (int gi = 0; gi < G; ++gi)
                acc[gi][t] = __builtin_amdgcn_mfma_f32_16x16x32_bf16(a[gi], bfr[t], acc[gi][t], 0, 0, 0);
    }

    int n0 = g << 7;
    int cb = n0 + l16 * 8;
    float sv[8], dv[8];
#pragma unroll
    for (int t = 0; t < 8; ++t) {
        sv[t] = asrc[cb + t];
        dv[t] = adst[cb + t];
    }
#pragma unroll
    for (int gi = 0; gi < G; ++gi) {
        int mt = mt0 + gi;
        if (mt >= mtiles) break;
        int row0 = mt * 16 + quad * 4;
#pragma unroll
        for (int r = 0; r < 4; ++r) {
            float sa = 0.f, sd = 0.f;
#pragma unroll
            for (int t = 0; t < 8; ++t) {
                sa += acc[gi][t][r] * sv[t];
                sd += acc[gi][t][r] * dv[t];
            }
            unsigned int w0 = __builtin_amdgcn_cvt_pk_fp8_f32(acc[gi][0][r], acc[gi][1][r], 0, false);
            w0 = __builtin_amdgcn_cvt_pk_fp8_f32(acc[gi][2][r], acc[gi][3][r], w0, true);
            unsigned int w1 = __builtin_amdgcn_cvt_pk_fp8_f32(acc[gi][4][r], acc[gi][5][r], 0, false);
            w1 = __builtin_amdgcn_cvt_pk_fp8_f32(acc[gi][6][r], acc[gi][7][r], w1, true);
            *(uint2*)(C + (size_t)(row0 + r) * N + cb) = (uint2){w0, w1};
#pragma unroll
            for (int off = 8; off; off >>= 1) {
                sa += __shfl_xor(sa, off);
                sd += __shfl_xor(sd, off);
            }
            if (l16 == 0) {
                int row = row0 + r;
                asd[(size_t)row * 4 + g]     = sa * L2E;
                asd[(size_t)row * 4 + 2 + g] = sd * L2E;
            }
        }
    }
}

// ---------------- agg phase (v5 shape, measured-best): 16 dests/block -> LDS ----------------
// One dest per 16-lane group; lane owns a fixed 16B slice; zero cross-lane ops.
// (Round-17 lesson: half-group split doubled acc -> VGPR 68 -> occupancy tier
// drop; this acc[8] / 44-VGPR shape is the local optimum.)
__device__ __forceinline__ void agg16_to_lds(const int* __restrict__ rs,
                                             const int* __restrict__ csr,
                                             const unsigned char* __restrict__ h,
                                             const float* __restrict__ asd,
                                             const float* __restrict__ bias,
                                             unsigned short* __restrict__ sA,
                                             int rowbase, int M, int tid) {
    int grp = tid >> 4;
    int sub = tid & 15;
    int d = rowbase + grp;
    if (d >= M) return;   // device-fn return only skips agg work; barriers are in caller
    int head = sub >> 3;
    int beg = rs[d], end = rs[d + 1];
    float adh = asd[(size_t)d * 4 + 2 + head];
    int cbase = sub * 16;
    const unsigned char* hc = h + cbase;
    v2f acc[8];
#pragma unroll
    for (int j = 0; j < 8; ++j) acc[j] = (v2f){0, 0};
    float den = 0.f;
#pragma unroll 2
    for (int i = beg; i < end; ++i) {
        int s = csr[i];
        float wgt = __builtin_amdgcn_exp2f(lrelu(asd[(size_t)s * 4 + head] + adh));
        den += wgt;
        uint4 u = *(const uint4*)(hc + ((size_t)s << 8));
        v2f w2 = {wgt, wgt};
        acc[0] += w2 * __builtin_amdgcn_cvt_pk_f32_fp8(u.x, false);
        acc[1] += w2 * __builtin_amdgcn_cvt_pk_f32_fp8(u.x, true);
        acc[2] += w2 * __builtin_amdgcn_cvt_pk_f32_fp8(u.y, false);
        acc[3] += w2 * __builtin_amdgcn_cvt_pk_f32_fp8(u.y, true);
        acc[4] += w2 * __builtin_amdgcn_cvt_pk_f32_fp8(u.z, false);
        acc[5] += w2 * __builtin_amdgcn_cvt_pk_f32_fp8(u.z, true);
        acc[6] += w2 * __builtin_amdgcn_cvt_pk_f32_fp8(u.w, false);
        acc[7] += w2 * __builtin_amdgcn_cvt_pk_f32_fp8(u.w, true);
    }
    // self-loop term (src = d), not present in csr
    float wS = __builtin_amdgcn_exp2f(lrelu(asd[(size_t)d * 4 + head] + adh));
    {
        uint4 u = *(const uint4*)(hc + ((size_t)d << 8));
        v2f wsv = {wS, wS};
        acc[0] += wsv * __builtin_amdgcn_cvt_pk_f32_fp8(u.x, false);
        acc[1] += wsv * __builtin_amdgcn_cvt_pk_f32_fp8(u.x, true);
        acc[2] += wsv * __builtin_amdgcn_cvt_pk_f32_fp8(u.y, false);
        acc[3] += wsv * __builtin_amdgcn_cvt_pk_f32_fp8(u.y, true);
        acc[4] += wsv * __builtin_amdgcn_cvt_pk_f32_fp8(u.z, false);
        acc[5] += wsv * __builtin_amdgcn_cvt_pk_f32_fp8(u.z, true);
        acc[6] += wsv * __builtin_amdgcn_cvt_pk_f32_fp8(u.w, false);
        acc[7] += wsv * __builtin_amdgcn_cvt_pk_f32_fp8(u.w, true);
    }
    float rden = 1.f / (den + wS + 1e-16f);
    us8 o0, o1;
#pragma unroll
    for (int j = 0; j < 4; ++j) {
        o0[2 * j]     = f2bf(fmaxf(acc[j].x * rden + bias[cbase + 2 * j], 0.f));
        o0[2 * j + 1] = f2bf(fmaxf(acc[j].y * rden + bias[cbase + 2 * j + 1], 0.f));
        o1[2 * j]     = f2bf(fmaxf(acc[4 + j].x * rden + bias[cbase + 8 + 2 * j], 0.f));
        o1[2 * j + 1] = f2bf(fmaxf(acc[4 + j].y * rden + bias[cbase + 8 + 2 * j + 1], 0.f));
    }
    unsigned short* dst = sA + grp * LROW + cbase;
    *(us8*)dst = o0;
    *(us8*)(dst + 8) = o1;
}

// ---------------- fused: agg(L1) -> LDS -> gemm(L2) tile b ----------------
// ALL 4 waves active in the gemm phase (wave wv -> group g=wv&1, frag-half
// hh=wv>>1, 4 frags each). Alpha-dot halves combine via small LDS + 2nd barrier.
template<int KSTEPS>
__global__ __launch_bounds__(256) void fused_agg_gemm(const int* __restrict__ rs,
                                                      const int* __restrict__ csr,
                                                      const unsigned char* __restrict__ hIn,
                                                      const float* __restrict__ asdIn,
                                                      const float* __restrict__ biasIn,
                                                      const unsigned short* __restrict__ Bp,
                                                      const float* __restrict__ asrc,
                                                      const float* __restrict__ adst,
                                                      float* __restrict__ asdOut,
                                                      unsigned char* __restrict__ C,
                                                      int M) {
    __shared__ __align__(16) unsigned short sA[16 * LROW];
    __shared__ float sS[2][2][16], sD[2][2][16];   // [hh][g][row16]
    int tid = threadIdx.x;
    int rowbase = blockIdx.x * 16;
    agg16_to_lds(rs, csr, hIn, asdIn, biasIn, sA, rowbase, M, tid);
    __syncthreads();

    int wv = tid >> 6;
    int g  = wv & 1;                      // n-group 0/1
    int hh = wv >> 1;                     // frag half 0/1
    int lane = tid & 63;
    int l16 = lane & 15, quad = lane >> 4;

    const unsigned short* Bf = Bp + ((size_t)(g * 8) * KSTEPS << 9) + lane * 8;
    v4f acc[4];
#pragma unroll
    for (int t = 0; t < 4; ++t) acc[t] = (v4f){0, 0, 0, 0};
#pragma unroll
    for (int k0 = 0; k0 < KSTEPS; ++k0) {
        v8bf bfr[4];
#pragma unroll
        for (int t = 0; t < 4; ++t)
            bfr[t] = *(const v8bf*)(Bf + ((size_t)((hh * 4 + t) * KSTEPS + k0) << 9));
        v8bf a = *(const v8bf*)(sA + l16 * LROW + k0 * 32 + quad * 8);
#pragma unroll
        for (int t = 0; t < 4; ++t)
            acc[t] = __builtin_amdgcn_mfma_f32_16x16x32_bf16(a, bfr[t], acc[t], 0, 0, 0);
    }

    int n0 = g << 7;
    int cb = n0 + l16 * 8 + hh * 4;       // this wave's 4 consecutive cols
    float sv[4], dv[4];
#pragma unroll
    for (int t = 0; t < 4; ++t) {
        sv[t] = asrc[cb + t];
        dv[t] = adst[cb + t];
    }
    int row0q = quad * 4;
#pragma unroll
    for (int r = 0; r < 4; ++r) {
        float sa = 0.f, sd = 0.f;
#pragma unroll
        for (int t = 0; t < 4; ++t) {
            sa += acc[t][r] * sv[t];
            sd += acc[t][r] * dv[t];
        }
        unsigned int w0 = __builtin_amdgcn_cvt_pk_fp8_f32(acc[0][r], acc[1][r], 0, false);
        w0 = __builtin_amdgcn_cvt_pk_fp8_f32(acc[2][r], acc[3][r], w0, true);
        *(unsigned int*)(C + (size_t)(rowbase + row0q + r) * C2 + cb) = w0;
#pragma unroll
        for (int off = 8; off; off >>= 1) {
            sa += __shfl_xor(sa, off);
            sd += __shfl_xor(sd, off);
        }
        if (l16 == 0) {
            sS[hh][g][row0q + r] = sa;
            sD[hh][g][row0q + r] = sd;
        }
    }
    __syncthreads();
    if (tid < 32) {
        int row16 = tid & 15, gg = tid >> 4;
        float sa = (sS[0][gg][row16] + sS[1][gg][row16]) * L2E;
        float sd = (sD[0][gg][row16] + sD[1][gg][row16]) * L2E;
        int row = rowbase + row16;
        asdOut[(size_t)row * 4 + gg]     = sa;
        asdOut[(size_t)row * 4 + 2 + gg] = sd;
    }
}

// ---------------- fused: agg(L2) -> LDS -> post-MLP tile b ----------------
// ALL 4 waves active in the MLP phase (wave wv -> frags {2wv, 2wv+1}).
template<int KSTEPS>
__global__ __launch_bounds__(256) void fused_agg_final(const int* __restrict__ rs,
                                                       const int* __restrict__ csr,
                                                       const unsigned char* __restrict__ hIn,
                                                       const float* __restrict__ asdIn,
                                                       const float* __restrict__ biasIn,
                                                       const unsigned short* __restrict__ Bp,
                                                       const float* __restrict__ bp1,
                                                       const float* __restrict__ wp2,
                                                       const float* __restrict__ bp2,
                                                       float* __restrict__ out,
                                                       int M) {
    __shared__ __align__(16) unsigned short sA[16 * LROW];
    __shared__ float sF[4][16];
    int tid = threadIdx.x;
    int rowbase = blockIdx.x * 16;
    agg16_to_lds(rs, csr, hIn, asdIn, biasIn, sA, rowbase, M, tid);
    __syncthreads();

    int wv = tid >> 6;
    int lane = tid & 63;
    int l16 = lane & 15, quad = lane >> 4;

    const unsigned short* Bf = Bp + lane * 8;
    v4f acc[2];
#pragma unroll
    for (int t = 0; t < 2; ++t) acc[t] = (v4f){0, 0, 0, 0};
#pragma unroll
    for (int k0 = 0; k0 < KSTEPS; ++k0) {
        v8bf a = *(const v8bf*)(sA + l16 * LROW + k0 * 32 + quad * 8);
#pragma unroll
        for (int t = 0; t < 2; ++t) {
            v8bf bfr = *(const v8bf*)(Bf + ((size_t)((wv * 2 + t) * KSTEPS + k0) << 9));
            acc[t] = __builtin_amdgcn_mfma_f32_16x16x32_bf16(a, bfr, acc[t], 0, 0, 0);
        }
    }
    int cb = l16 * 8;
    float wv2[2], bv2[2];
#pragma unroll
    for (int t = 0; t < 2; ++t) {
        wv2[t] = wp2[cb + wv * 2 + t];
        bv2[t] = bp1[cb + wv * 2 + t];
    }
    int row0q = quad * 4;
#pragma unroll
    for (int r = 0; r < 4; ++r) {
        float s = (acc[0][r] + bv2[0]) * wv2[0] + (acc[1][r] + bv2[1]) * wv2[1];
#pragma unroll
        for (int off = 8; off; off >>= 1) s += __shfl_xor(s, off);
        if (l16 == 0) sF[wv][row0q + r] = s;
    }
    __syncthreads();
    if (tid < 16) {
        float s = sF[0][tid] + sF[1][tid] + sF[2][tid] + sF[3][tid] + bp2[0];
        out[rowbase + tid] = 1.f / (1.f + __expf(-s));
    }
}

extern "C" void kernel_launch(void* const* d_in, const int* in_sizes, int n_in,
                              void* d_out, int out_size, void* d_ws, size_t ws_size,
                              hipStream_t stream) {
    const float* x   = (const float*)d_in[0];
    const int*   ei  = (const int*)d_in[1];
    const float* W1  = (const float*)d_in[2];
    const float* as1 = (const float*)d_in[3];
    const float* ad1 = (const float*)d_in[4];
    const float* b1  = (const float*)d_in[5];
    const float* W2  = (const float*)d_in[6];
    const float* as2 = (const float*)d_in[7];
    const float* ad2 = (const float*)d_in[8];
    const float* b2  = (const float*)d_in[9];
    const float* Wp1 = (const float*)d_in[10];
    const float* bp1 = (const float*)d_in[11];
    const float* Wp2 = (const float*)d_in[12];
    const float* bp2 = (const float*)d_in[13];
    float* out = (float*)d_out;

    int NN = in_sizes[0] / HID;   // 50000
    int E  = in_sizes[1] / 2;     // 800000

    char* ws = (char*)d_ws;
    size_t off = 0;
    auto alloc = [&](size_t bytes) -> char* {
        char* p = ws + off;
        off += (bytes + 255) & ~(size_t)255;
        return p;
    };
    unsigned char*  bufH1 = (unsigned char*)alloc((size_t)NN * C2);      // h1, fp8 e4m3
    unsigned char*  bufH2 = (unsigned char*)alloc((size_t)NN * C2);      // h2, fp8 e4m3
    float* asd1 = (float*)alloc((size_t)NN * 4 * sizeof(float));
    float* asd2 = (float*)alloc((size_t)NN * 4 * sizeof(float));
    int* rs    = (int*)alloc((size_t)(NN + 1) * 4);
    int* cnt   = (int*)alloc((size_t)NN * 4);
    int* rank  = (int*)alloc((size_t)E * 4);
    int* csr   = (int*)alloc((size_t)E * 4);
    int* part  = (int*)alloc(1024);
    unsigned short* W1p  = (unsigned short*)alloc((size_t)HID * C2 * 2);  // packed
    unsigned short* W2p  = (unsigned short*)alloc((size_t)C2 * C2 * 2);
    unsigned short* Wp1p = (unsigned short*)alloc((size_t)C2 * HID * 2);

    int nchunk = (NN + 255) / 256;
    int eblk   = (E + 255) / 256;

    // prep: weight packing + hist/rank (fused)
    int pb1 = (HID * C2 / 8 + 255) / 256;
    int pb2 = (C2 * C2 / 8 + 255) / 256;
    int pb3 = (C2 * HID / 8 + 255) / 256;
    hipMemsetAsync(cnt, 0, (size_t)NN * 4, stream);
    prep_kernel<<<pb1 + pb2 + pb3 + eblk, 256, 0, stream>>>(W1, W1p, W2, W2p, Wp1, Wp1p,
                                                            ei, cnt, rank, E, pb1, pb2, pb3);
    scanA<<<nchunk, 256, 0, stream>>>(cnt, rs, part, NN);
    scanBC<<<nchunk, 256, 0, stream>>>(rs, part, NN, E, nchunk);

    const int G = 1;
    int mtiles = NN / 16;                     // 3125
    int gemmBlocks = (mtiles * 2 + 3) / 4;    // 1563 (ngrp=2)
    int fuseGrid = mtiles;                    // 3125: agg grid preserved

    // layer 1 (A = fp32 x, K=128) + fused alpha dots, scatter piggy-backed
    gemm_alpha<true, G, 4><<<gemmBlocks + eblk, 256, 0, stream>>>(x, W1p, as1, ad1, asd1, bufH1,
                                                                  NN, C2, gemmBlocks,
                                                                  ei, rs, rank, csr, E);
    // fused: agg(L1) -> LDS -> gemm(L2)+alpha  (reads h1/asd1, writes h2/asd2)
    fused_agg_gemm<8><<<fuseGrid, 256, 0, stream>>>(rs, csr, bufH1, asd1, b1,
                                                    W2p, as2, ad2, asd2, bufH2, NN);
    // fused: agg(L2) -> LDS -> post-MLP
    fused_agg_final<8><<<fuseGrid, 256, 0, stream>>>(rs, csr, bufH2, asd2, b2,
                                                     Wp1p, bp1, Wp2, bp2, out, NN);
}

// Round 19
// 251.773 us; speedup vs baseline: 1.0619x; 1.0182x over previous
//
#include <hip/hip_runtime.h>

#define HID 128
#define C2 256   // HEADS*HID
#define NEG 0.2f
#define L2E 1.44269504088896340736f
#define LROW 264  // LDS row stride in shorts: 16B-aligned, breaks 256-stride bank pattern

typedef __bf16 v8bf __attribute__((ext_vector_type(8)));
typedef float  v4f  __attribute__((ext_vector_type(4)));
typedef float  v2f  __attribute__((ext_vector_type(2)));
typedef unsigned short us8 __attribute__((ext_vector_type(8)));

__device__ __forceinline__ float bf2f(unsigned short u) {
    union { float f; unsigned int i; } v; v.i = ((unsigned int)u) << 16; return v.f;
}
__device__ __forceinline__ unsigned short f2bf(float f) {
    union { float f; unsigned int i; } v; v.f = f;
    unsigned int r = v.i + 0x7FFFu + ((v.i >> 16) & 1u);
    return (unsigned short)(r >> 16);
}
__device__ __forceinline__ float lrelu(float x) { return x > 0.f ? x : NEG * x; }

// ---------------- prep: 3x packB + hist_rank fused ----------------
__device__ __forceinline__ void packB_body(const float* __restrict__ W,
                                           unsigned short* __restrict__ out,
                                           int K, int N, int idx) {
    int ksteps = K >> 5;
    int total = (N >> 4) * ksteps * 64;
    if (idx >= total) return;
    int lane = idx & 63;
    int rest = idx >> 6;
    int tt = rest / ksteps, k0 = rest - tt * ksteps;
    int n = (tt >> 3) * 128 + (lane & 15) * 8 + (tt & 7);
    int kb = k0 * 32 + (lane >> 4) * 8;
    us8 v;
#pragma unroll
    for (int j = 0; j < 8; ++j) v[j] = f2bf(W[(size_t)(kb + j) * N + n]);
    *(us8*)(out + (size_t)idx * 8) = v;
}

__global__ __launch_bounds__(256) void prep_kernel(const float* __restrict__ W1, unsigned short* W1p,
                                                   const float* __restrict__ W2, unsigned short* W2p,
                                                   const float* __restrict__ Wp1, unsigned short* Wp1p,
                                                   const int* __restrict__ ei, int* __restrict__ cnt,
                                                   int* __restrict__ rank, int E,
                                                   int b1, int b2, int b3) {
    int b = blockIdx.x;
    if (b < b1) { packB_body(W1, W1p, HID, C2, b * 256 + threadIdx.x); return; }
    b -= b1;
    if (b < b2) { packB_body(W2, W2p, C2, C2, b * 256 + threadIdx.x); return; }
    b -= b2;
    if (b < b3) { packB_body(Wp1, Wp1p, C2, HID, b * 256 + threadIdx.x); return; }
    b -= b3;
    int i = b * 256 + threadIdx.x;
    if (i >= E) return;
    int d = ei[E + i];
    rank[i] = atomicAdd(&cnt[d], 1);
}

// ---------------- scans: scanA + merged scanBC ----------------
__global__ __launch_bounds__(256) void scanA(const int* __restrict__ cnt, int* __restrict__ rs,
                                             int* __restrict__ part, int N) {
    __shared__ int s[256];
    int t = threadIdx.x, i = blockIdx.x * 256 + t;
    int v = (i < N) ? cnt[i] : 0;
    s[t] = v; __syncthreads();
    for (int off = 1; off < 256; off <<= 1) {
        int x = (t >= off) ? s[t - off] : 0;
        __syncthreads();
        s[t] += x;
        __syncthreads();
    }
    if (i < N) rs[i] = s[t] - v;
    if (t == 255) part[blockIdx.x] = s[255];
}

__global__ __launch_bounds__(256) void scanBC(int* __restrict__ rs, const int* __restrict__ part,
                                              int N, int E, int nchunk) {
    __shared__ int ls[256];
    int t = threadIdx.x;
    int v = (t < nchunk) ? part[t] : 0;
    ls[t] = v; __syncthreads();
    for (int off = 1; off < 256; off <<= 1) {
        int x = (t >= off) ? ls[t - off] : 0;
        __syncthreads();
        ls[t] += x;
        __syncthreads();
    }
    int base = (blockIdx.x > 0) ? ls[blockIdx.x - 1] : 0;
    int i = blockIdx.x * 256 + t;
    if (i < N) rs[i] += base;
    if (i == 0) rs[N] = E;
}

// ---------------- GEMM layer 1: fused alpha dots + coalesced fp8 store ----------------
template<bool AFP32, int G, int KSTEPS>
__global__ __launch_bounds__(256) void gemm_alpha(const void* __restrict__ Av,
                                                  const unsigned short* __restrict__ Bp,
                                                  const float* __restrict__ asrc,
                                                  const float* __restrict__ adst,
                                                  float* __restrict__ asd,
                                                  unsigned char* __restrict__ C,
                                                  int M, int N, int gemmBlocks,
                                                  const int* __restrict__ ei,
                                                  const int* __restrict__ rs,
                                                  const int* __restrict__ rank,
                                                  int* __restrict__ csr, int E) {
    if (blockIdx.x >= gemmBlocks) {
        int i = (blockIdx.x - gemmBlocks) * 256 + threadIdx.x;
        if (i < E) {
            int s = ei[i], d = ei[E + i];
            csr[rs[d] + rank[i]] = s;
        }
        return;
    }
    constexpr int K = KSTEPS * 32;
    int ngrp = N >> 7;
    int mtiles = M >> 4;
    int w = (blockIdx.x << 2) + (threadIdx.x >> 6);
    int groups = (mtiles + G - 1) / G;
    int mp = w / ngrp, g = w - mp * ngrp;
    if (mp >= groups) return;
    int lane = threadIdx.x & 63;
    int l16 = lane & 15, quad = lane >> 4;
    int mt0 = mp * G;

    int mrow[G];
#pragma unroll
    for (int gi = 0; gi < G; ++gi) {
        int mt = mt0 + gi;
        mrow[gi] = (mt < mtiles ? mt : mtiles - 1) * 16 + l16;
    }

    const unsigned short* Bf = Bp + ((size_t)(g * 8) * KSTEPS << 9) + lane * 8;
    v4f acc[G][8];
#pragma unroll
    for (int gi = 0; gi < G; ++gi)
#pragma unroll
        for (int t = 0; t < 8; ++t) acc[gi][t] = (v4f){0, 0, 0, 0};

#pragma unroll
    for (int k0 = 0; k0 < KSTEPS; ++k0) {
        v8bf bfr[8];
#pragma unroll
        for (int t = 0; t < 8; ++t)
            bfr[t] = *(const v8bf*)(Bf + ((size_t)(t * KSTEPS + k0) << 9));
        v8bf a[G];
        if (AFP32) {
            const float* A = (const float*)Av;
#pragma unroll
            for (int gi = 0; gi < G; ++gi) {
                const float* p = A + (size_t)mrow[gi] * K + k0 * 32 + quad * 8;
                float4 u0 = *(const float4*)p, u1 = *(const float4*)(p + 4);
                a[gi][0]=(__bf16)u0.x; a[gi][1]=(__bf16)u0.y; a[gi][2]=(__bf16)u0.z; a[gi][3]=(__bf16)u0.w;
                a[gi][4]=(__bf16)u1.x; a[gi][5]=(__bf16)u1.y; a[gi][6]=(__bf16)u1.z; a[gi][7]=(__bf16)u1.w;
            }
        } else {
            const unsigned short* A = (const unsigned short*)Av;
#pragma unroll
            for (int gi = 0; gi < G; ++gi)
                a[gi] = *(const v8bf*)(A + (size_t)mrow[gi] * K + k0 * 32 + quad * 8);
        }
#pragma unroll
        for (int t = 0; t < 8; ++t)
#pragma unroll
            for (int gi = 0; gi < G; ++gi)
                acc[gi][t] = __builtin_amdgcn_mfma_f32_16x16x32_bf16(a[gi], bfr[t], acc[gi][t], 0, 0, 0);
    }

    int n0 = g << 7;
    int cb = n0 + l16 * 8;
    float sv[8], dv[8];
#pragma unroll
    for (int t = 0; t < 8; ++t) {
        sv[t] = asrc[cb + t];
        dv[t] = adst[cb + t];
    }
#pragma unroll
    for (int gi = 0; gi < G; ++gi) {
        int mt = mt0 + gi;
        if (mt >= mtiles) break;
        int row0 = mt * 16 + quad * 4;
#pragma unroll
        for (int r = 0; r < 4; ++r) {
            float sa = 0.f, sd = 0.f;
#pragma unroll
            for (int t = 0; t < 8; ++t) {
                sa += acc[gi][t][r] * sv[t];
                sd += acc[gi][t][r] * dv[t];
            }
            unsigned int w0 = __builtin_amdgcn_cvt_pk_fp8_f32(acc[gi][0][r], acc[gi][1][r], 0, false);
            w0 = __builtin_amdgcn_cvt_pk_fp8_f32(acc[gi][2][r], acc[gi][3][r], w0, true);
            unsigned int w1 = __builtin_amdgcn_cvt_pk_fp8_f32(acc[gi][4][r], acc[gi][5][r], 0, false);
            w1 = __builtin_amdgcn_cvt_pk_fp8_f32(acc[gi][6][r], acc[gi][7][r], w1, true);
            *(uint2*)(C + (size_t)(row0 + r) * N + cb) = (uint2){w0, w1};
#pragma unroll
            for (int off = 8; off; off >>= 1) {
                sa += __shfl_xor(sa, off);
                sd += __shfl_xor(sd, off);
            }
            if (l16 == 0) {
                int row = row0 + r;
                asd[(size_t)row * 4 + g]     = sa * L2E;
                asd[(size_t)row * 4 + 2 + g] = sd * L2E;
            }
        }
    }
}

// ---------------- agg phase (v5 shape + s/asd software pipeline) ----------------
// One dest per 16-lane group; lane owns a fixed 16B slice; zero cross-lane ops.
// NEW: csr[i+1] and asd[snext] are prefetched one iteration ahead so the
// csr->asd dependent-load chain overlaps iteration i's weight+gather work
// (chain was the last un-attacked latency term; parallelism-shape levers all
// falsified r9/r11/r17). Index clamped to end-1: no OOB, loop skipped if empty.
__device__ __forceinline__ void agg16_to_lds(const int* __restrict__ rs,
                                             const int* __restrict__ csr,
                                             const unsigned char* __restrict__ h,
                                             const float* __restrict__ asd,
                                             const float* __restrict__ bias,
                                             unsigned short* __restrict__ sA,
                                             int rowbase, int M, int tid) {
    int grp = tid >> 4;
    int sub = tid & 15;
    int d = rowbase + grp;
    if (d >= M) return;   // device-fn return only skips agg work; barriers are in caller
    int head = sub >> 3;
    int beg = rs[d], end = rs[d + 1];
    float adh = asd[(size_t)d * 4 + 2 + head];
    int cbase = sub * 16;
    const unsigned char* hc = h + cbase;
    v2f acc[8];
#pragma unroll
    for (int j = 0; j < 8; ++j) acc[j] = (v2f){0, 0};
    float den = 0.f;
    int s = 0;
    float aspref = 0.f;
    if (beg < end) {
        s = csr[beg];
        aspref = asd[(size_t)s * 4 + head];
    }
#pragma unroll 2
    for (int i = beg; i < end; ++i) {
        int inext = (i + 1 < end) ? i + 1 : i;
        int snext = csr[inext];                              // prefetch next src
        float asnext = asd[(size_t)snext * 4 + head];        // prefetch next asd
        float wgt = __builtin_amdgcn_exp2f(lrelu(aspref + adh));
        den += wgt;
        uint4 u = *(const uint4*)(hc + ((size_t)s << 8));
        v2f w2 = {wgt, wgt};
        acc[0] += w2 * __builtin_amdgcn_cvt_pk_f32_fp8(u.x, false);
        acc[1] += w2 * __builtin_amdgcn_cvt_pk_f32_fp8(u.x, true);
        acc[2] += w2 * __builtin_amdgcn_cvt_pk_f32_fp8(u.y, false);
        acc[3] += w2 * __builtin_amdgcn_cvt_pk_f32_fp8(u.y, true);
        acc[4] += w2 * __builtin_amdgcn_cvt_pk_f32_fp8(u.z, false);
        acc[5] += w2 * __builtin_amdgcn_cvt_pk_f32_fp8(u.z, true);
        acc[6] += w2 * __builtin_amdgcn_cvt_pk_f32_fp8(u.w, false);
        acc[7] += w2 * __builtin_amdgcn_cvt_pk_f32_fp8(u.w, true);
        s = snext;
        aspref = asnext;
    }
    // self-loop term (src = d), not present in csr
    float wS = __builtin_amdgcn_exp2f(lrelu(asd[(size_t)d * 4 + head] + adh));
    {
        uint4 u = *(const uint4*)(hc + ((size_t)d << 8));
        v2f wsv = {wS, wS};
        acc[0] += wsv * __builtin_amdgcn_cvt_pk_f32_fp8(u.x, false);
        acc[1] += wsv * __builtin_amdgcn_cvt_pk_f32_fp8(u.x, true);
        acc[2] += wsv * __builtin_amdgcn_cvt_pk_f32_fp8(u.y, false);
        acc[3] += wsv * __builtin_amdgcn_cvt_pk_f32_fp8(u.y, true);
        acc[4] += wsv * __builtin_amdgcn_cvt_pk_f32_fp8(u.z, false);
        acc[5] += wsv * __builtin_amdgcn_cvt_pk_f32_fp8(u.z, true);
        acc[6] += wsv * __builtin_amdgcn_cvt_pk_f32_fp8(u.w, false);
        acc[7] += wsv * __builtin_amdgcn_cvt_pk_f32_fp8(u.w, true);
    }
    float rden = 1.f / (den + wS + 1e-16f);
    us8 o0, o1;
#pragma unroll
    for (int j = 0; j < 4; ++j) {
        o0[2 * j]     = f2bf(fmaxf(acc[j].x * rden + bias[cbase + 2 * j], 0.f));
        o0[2 * j + 1] = f2bf(fmaxf(acc[j].y * rden + bias[cbase + 2 * j + 1], 0.f));
        o1[2 * j]     = f2bf(fmaxf(acc[4 + j].x * rden + bias[cbase + 8 + 2 * j], 0.f));
        o1[2 * j + 1] = f2bf(fmaxf(acc[4 + j].y * rden + bias[cbase + 8 + 2 * j + 1], 0.f));
    }
    unsigned short* dst = sA + grp * LROW + cbase;
    *(us8*)dst = o0;
    *(us8*)(dst + 8) = o1;
}

// ---------------- fused: agg(L1) -> LDS -> gemm(L2) tile b ----------------
// ALL 4 waves active in the gemm phase (wave wv -> group g=wv&1, frag-half
// hh=wv>>1, 4 frags each). Alpha-dot halves combine via small LDS + 2nd barrier.
template<int KSTEPS>
__global__ __launch_bounds__(256) void fused_agg_gemm(const int* __restrict__ rs,
                                                      const int* __restrict__ csr,
                                                      const unsigned char* __restrict__ hIn,
                                                      const float* __restrict__ asdIn,
                                                      const float* __restrict__ biasIn,
                                                      const unsigned short* __restrict__ Bp,
                                                      const float* __restrict__ asrc,
                                                      const float* __restrict__ adst,
                                                      float* __restrict__ asdOut,
                                                      unsigned char* __restrict__ C,
                                                      int M) {
    __shared__ __align__(16) unsigned short sA[16 * LROW];
    __shared__ float sS[2][2][16], sD[2][2][16];   // [hh][g][row16]
    int tid = threadIdx.x;
    int rowbase = blockIdx.x * 16;
    agg16_to_lds(rs, csr, hIn, asdIn, biasIn, sA, rowbase, M, tid);
    __syncthreads();

    int wv = tid >> 6;
    int g  = wv & 1;                      // n-group 0/1
    int hh = wv >> 1;                     // frag half 0/1
    int lane = tid & 63;
    int l16 = lane & 15, quad = lane >> 4;

    const unsigned short* Bf = Bp + ((size_t)(g * 8) * KSTEPS << 9) + lane * 8;
    v4f acc[4];
#pragma unroll
    for (int t = 0; t < 4; ++t) acc[t] = (v4f){0, 0, 0, 0};
#pragma unroll
    for (int k0 = 0; k0 < KSTEPS; ++k0) {
        v8bf bfr[4];
#pragma unroll
        for (int t = 0; t < 4; ++t)
            bfr[t] = *(const v8bf*)(Bf + ((size_t)((hh * 4 + t) * KSTEPS + k0) << 9));
        v8bf a = *(const v8bf*)(sA + l16 * LROW + k0 * 32 + quad * 8);
#pragma unroll
        for (int t = 0; t < 4; ++t)
            acc[t] = __builtin_amdgcn_mfma_f32_16x16x32_bf16(a, bfr[t], acc[t], 0, 0, 0);
    }

    int n0 = g << 7;
    int cb = n0 + l16 * 8 + hh * 4;       // this wave's 4 consecutive cols
    float sv[4], dv[4];
#pragma unroll
    for (int t = 0; t < 4; ++t) {
        sv[t] = asrc[cb + t];
        dv[t] = adst[cb + t];
    }
    int row0q = quad * 4;
#pragma unroll
    for (int r = 0; r < 4; ++r) {
        float sa = 0.f, sd = 0.f;
#pragma unroll
        for (int t = 0; t < 4; ++t) {
            sa += acc[t][r] * sv[t];
            sd += acc[t][r] * dv[t];
        }
        unsigned int w0 = __builtin_amdgcn_cvt_pk_fp8_f32(acc[0][r], acc[1][r], 0, false);
        w0 = __builtin_amdgcn_cvt_pk_fp8_f32(acc[2][r], acc[3][r], w0, true);
        *(unsigned int*)(C + (size_t)(rowbase + row0q + r) * C2 + cb) = w0;
#pragma unroll
        for (int off = 8; off; off >>= 1) {
            sa += __shfl_xor(sa, off);
            sd += __shfl_xor(sd, off);
        }
        if (l16 == 0) {
            sS[hh][g][row0q + r] = sa;
            sD[hh][g][row0q + r] = sd;
        }
    }
    __syncthreads();
    if (tid < 32) {
        int row16 = tid & 15, gg = tid >> 4;
        float sa = (sS[0][gg][row16] + sS[1][gg][row16]) * L2E;
        float sd = (sD[0][gg][row16] + sD[1][gg][row16]) * L2E;
        int row = rowbase + row16;
        asdOut[(size_t)row * 4 + gg]     = sa;
        asdOut[(size_t)row * 4 + 2 + gg] = sd;
    }
}

// ---------------- fused: agg(L2) -> LDS -> post-MLP tile b ----------------
// ALL 4 waves active in the MLP phase (wave wv -> frags {2wv, 2wv+1}).
template<int KSTEPS>
__global__ __launch_bounds__(256) void fused_agg_final(const int* __restrict__ rs,
                                                       const int* __restrict__ csr,
                                                       const unsigned char* __restrict__ hIn,
                                                       const float* __restrict__ asdIn,
                                                       const float* __restrict__ biasIn,
                                                       const unsigned short* __restrict__ Bp,
                                                       const float* __restrict__ bp1,
                                                       const float* __restrict__ wp2,
                                                       const float* __restrict__ bp2,
                                                       float* __restrict__ out,
                                                       int M) {
    __shared__ __align__(16) unsigned short sA[16 * LROW];
    __shared__ float sF[4][16];
    int tid = threadIdx.x;
    int rowbase = blockIdx.x * 16;
    agg16_to_lds(rs, csr, hIn, asdIn, biasIn, sA, rowbase, M, tid);
    __syncthreads();

    int wv = tid >> 6;
    int lane = tid & 63;
    int l16 = lane & 15, quad = lane >> 4;

    const unsigned short* Bf = Bp + lane * 8;
    v4f acc[2];
#pragma unroll
    for (int t = 0; t < 2; ++t) acc[t] = (v4f){0, 0, 0, 0};
#pragma unroll
    for (int k0 = 0; k0 < KSTEPS; ++k0) {
        v8bf a = *(const v8bf*)(sA + l16 * LROW + k0 * 32 + quad * 8);
#pragma unroll
        for (int t = 0; t < 2; ++t) {
            v8bf bfr = *(const v8bf*)(Bf + ((size_t)((wv * 2 + t) * KSTEPS + k0) << 9));
            acc[t] = __builtin_amdgcn_mfma_f32_16x16x32_bf16(a, bfr, acc[t], 0, 0, 0);
        }
    }
    int cb = l16 * 8;
    float wv2[2], bv2[2];
#pragma unroll
    for (int t = 0; t < 2; ++t) {
        wv2[t] = wp2[cb + wv * 2 + t];
        bv2[t] = bp1[cb + wv * 2 + t];
    }
    int row0q = quad * 4;
#pragma unroll
    for (int r = 0; r < 4; ++r) {
        float s = (acc[0][r] + bv2[0]) * wv2[0] + (acc[1][r] + bv2[1]) * wv2[1];
#pragma unroll
        for (int off = 8; off; off >>= 1) s += __shfl_xor(s, off);
        if (l16 == 0) sF[wv][row0q + r] = s;
    }
    __syncthreads();
    if (tid < 16) {
        float s = sF[0][tid] + sF[1][tid] + sF[2][tid] + sF[3][tid] + bp2[0];
        out[rowbase + tid] = 1.f / (1.f + __expf(-s));
    }
}

extern "C" void kernel_launch(void* const* d_in, const int* in_sizes, int n_in,
                              void* d_out, int out_size, void* d_ws, size_t ws_size,
                              hipStream_t stream) {
    const float* x   = (const float*)d_in[0];
    const int*   ei  = (const int*)d_in[1];
    const float* W1  = (const float*)d_in[2];
    const float* as1 = (const float*)d_in[3];
    const float* ad1 = (const float*)d_in[4];
    const float* b1  = (const float*)d_in[5];
    const float* W2  = (const float*)d_in[6];
    const float* as2 = (const float*)d_in[7];
    const float* ad2 = (const float*)d_in[8];
    const float* b2  = (const float*)d_in[9];
    const float* Wp1 = (const float*)d_in[10];
    const float* bp1 = (const float*)d_in[11];
    const float* Wp2 = (const float*)d_in[12];
    const float* bp2 = (const float*)d_in[13];
    float* out = (float*)d_out;

    int NN = in_sizes[0] / HID;   // 50000
    int E  = in_sizes[1] / 2;     // 800000

    char* ws = (char*)d_ws;
    size_t off = 0;
    auto alloc = [&](size_t bytes) -> char* {
        char* p = ws + off;
        off += (bytes + 255) & ~(size_t)255;
        return p;
    };
    unsigned char*  bufH1 = (unsigned char*)alloc((size_t)NN * C2);      // h1, fp8 e4m3
    unsigned char*  bufH2 = (unsigned char*)alloc((size_t)NN * C2);      // h2, fp8 e4m3
    float* asd1 = (float*)alloc((size_t)NN * 4 * sizeof(float));
    float* asd2 = (float*)alloc((size_t)NN * 4 * sizeof(float));
    int* rs    = (int*)alloc((size_t)(NN + 1) * 4);
    int* cnt   = (int*)alloc((size_t)NN * 4);
    int* rank  = (int*)alloc((size_t)E * 4);
    int* csr   = (int*)alloc((size_t)E * 4);
    int* part  = (int*)alloc(1024);
    unsigned short* W1p  = (unsigned short*)alloc((size_t)HID * C2 * 2);  // packed
    unsigned short* W2p  = (unsigned short*)alloc((size_t)C2 * C2 * 2);
    unsigned short* Wp1p = (unsigned short*)alloc((size_t)C2 * HID * 2);

    int nchunk = (NN + 255) / 256;
    int eblk   = (E + 255) / 256;

    // prep: weight packing + hist/rank (fused)
    int pb1 = (HID * C2 / 8 + 255) / 256;
    int pb2 = (C2 * C2 / 8 + 255) / 256;
    int pb3 = (C2 * HID / 8 + 255) / 256;
    hipMemsetAsync(cnt, 0, (size_t)NN * 4, stream);
    prep_kernel<<<pb1 + pb2 + pb3 + eblk, 256, 0, stream>>>(W1, W1p, W2, W2p, Wp1, Wp1p,
                                                            ei, cnt, rank, E, pb1, pb2, pb3);
    scanA<<<nchunk, 256, 0, stream>>>(cnt, rs, part, NN);
    scanBC<<<nchunk, 256, 0, stream>>>(rs, part, NN, E, nchunk);

    const int G = 1;
    int mtiles = NN / 16;                     // 3125
    int gemmBlocks = (mtiles * 2 + 3) / 4;    // 1563 (ngrp=2)
    int fuseGrid = mtiles;                    // 3125: agg grid preserved

    // layer 1 (A = fp32 x, K=128) + fused alpha dots, scatter piggy-backed
    gemm_alpha<true, G, 4><<<gemmBlocks + eblk, 256, 0, stream>>>(x, W1p, as1, ad1, asd1, bufH1,
                                                                  NN, C2, gemmBlocks,
                                                                  ei, rs, rank, csr, E);
    // fused: agg(L1) -> LDS -> gemm(L2)+alpha  (reads h1/asd1, writes h2/asd2)
    fused_agg_gemm<8><<<fuseGrid, 256, 0, stream>>>(rs, csr, bufH1, asd1, b1,
                                                    W2p, as2, ad2, asd2, bufH2, NN);
    // fused: agg(L2) -> LDS -> post-MLP
    fused_agg_final<8><<<fuseGrid, 256, 0, stream>>>(rs, csr, bufH2, asd2, b2,
                                                     Wp1p, bp1, Wp2, bp2, out, NN);
}